// Round 2
// baseline (477.734 us; speedup 1.0000x reference)
//
#include <hip/hip_runtime.h>
#include <math.h>

// Problem constants (match reference)
namespace {
constexpr int B = 2, F = 32, T = 1024, D = 1024;
constexpr int H = 512, W = 512;
constexpr int HWN = H * W;                   // 262144 elements per (b,f) mask
constexpr float BASE_BLEND = 0.1f;           // 1 - DECAY
constexpr float COS_EPS = 1e-6f;
constexpr int COV_SUB = 16;                  // blocks per (b,f) mask slice
}

// ---------------------------------------------------------------------------
// Kernel 1: partial clip+sum of each mask slice. 16 blocks per (b,f) slice so
// the 64MB read uses all CUs. float4 loads, wave shuffle reduce, tiny LDS.
// ---------------------------------------------------------------------------
__global__ __launch_bounds__(256) void cov_partial_kernel(
    const float* __restrict__ masks, float* __restrict__ partial) {
  const int s   = blockIdx.x >> 4;           // (b*F + f) slice
  const int sub = blockIdx.x & (COV_SUB - 1);
  const float4* p = reinterpret_cast<const float4*>(masks) +
                    (size_t)s * (HWN / 4) + (size_t)sub * (HWN / 4 / COV_SUB);
  float sum = 0.f;
#pragma unroll
  for (int i = 0; i < 16; ++i) {             // 16 float4 per thread
    float4 v = p[i * 256 + threadIdx.x];
    sum += fminf(fmaxf(v.x, 0.f), 1.f);
    sum += fminf(fmaxf(v.y, 0.f), 1.f);
    sum += fminf(fmaxf(v.z, 0.f), 1.f);
    sum += fminf(fmaxf(v.w, 0.f), 1.f);
  }
#pragma unroll
  for (int m = 32; m; m >>= 1) sum += __shfl_xor(sum, m, 64);
  __shared__ float sw[4];
  if ((threadIdx.x & 63) == 0) sw[threadIdx.x >> 6] = sum;
  __syncthreads();
  if (threadIdx.x == 0) partial[blockIdx.x] = sw[0] + sw[1] + sw[2] + sw[3];
}

// ---------------------------------------------------------------------------
// Kernel 2: fold 16 partials per slice into the coverage mean (64 scalars).
// ---------------------------------------------------------------------------
__global__ void cov_final_kernel(const float* __restrict__ partial,
                                 float* __restrict__ cov) {
  const int i = threadIdx.x;                 // 0..63 == b*F + f
  float s = 0.f;
#pragma unroll
  for (int j = 0; j < COV_SUB; ++j) s += partial[i * COV_SUB + j];
  cov[i] = s * (1.0f / (float)HWN);
}

// ---------------------------------------------------------------------------
// Kernel 3: the scan. One BLOCK (256 thr, 4 waves) per (b,t) row; each lane
// holds 1 float4 of the D=1024 memory state -> tiny VGPR footprint, 2048
// blocks = 8 blocks/CU = 32 waves/CU. Cosine reduction: wave butterfly +
// 12-float LDS cross-wave fold, ONE barrier per frame (double-buffered LDS
// slots remove the WAR barrier). Next frame prefetched before the reduction.
// ---------------------------------------------------------------------------
#define DOT4(a, b) ((a).x * (b).x + (a).y * (b).y + (a).z * (b).z + (a).w * (b).w)

__global__ __launch_bounds__(256) void tracker_kernel(
    const float4* __restrict__ toks, const float* __restrict__ cov,
    float4* __restrict__ out) {
  const int tid = threadIdx.x;               // 0..255, float4 index in row
  const int wv  = tid >> 6;
  const int r   = blockIdx.x;                // row index: b*T + t
  const int b   = r >> 10;                   // T = 1024

  const size_t rowbase = ((size_t)(b * F * T) + (size_t)(r & 1023)) * (D / 4);
  const size_t fs      = (size_t)T * (D / 4);  // float4 stride between frames
  const float4* tp = toks + rowbase + tid;
  float4*       op = out  + rowbase + tid;
  const float* covp = cov + b * F;

  __shared__ float red[2][4][3];             // [slot][wave][dot,nc,nm]

  // f = 0: memory = tokens, copy through.
  float4 m = tp[0];
  op[0] = m;

  // prefetch f = 1
  float4 c = tp[fs];

  for (int f = 1; f < F; ++f) {
    // prefetch f+1 while we reduce/compute on f
    float4 n;
    if (f + 1 < F) n = tp[(size_t)(f + 1) * fs];

    float dot = DOT4(c, m);
    float nc  = DOT4(c, c);
    float nm  = DOT4(m, m);
#pragma unroll
    for (int msk = 32; msk; msk >>= 1) {
      dot += __shfl_xor(dot, msk, 64);
      nc  += __shfl_xor(nc,  msk, 64);
      nm  += __shfl_xor(nm,  msk, 64);
    }
    const int slot = f & 1;
    if ((tid & 63) == 0) {
      red[slot][wv][0] = dot;
      red[slot][wv][1] = nc;
      red[slot][wv][2] = nm;
    }
    __syncthreads();
    dot = red[slot][0][0] + red[slot][1][0] + red[slot][2][0] + red[slot][3][0];
    nc  = red[slot][0][1] + red[slot][1][1] + red[slot][2][1] + red[slot][3][1];
    nm  = red[slot][0][2] + red[slot][1][2] + red[slot][2][2] + red[slot][3][2];

    const float sim = dot / (fmaxf(sqrtf(nc), COS_EPS) * fmaxf(sqrtf(nm), COS_EPS));
    float gate = 1.0f / (1.0f + expf(-sim / 0.07f));
    gate *= 0.5f + 0.5f * covp[f];
    float bl = BASE_BLEND * (0.5f + gate);
    bl = fminf(fmaxf(bl, 0.0f), 1.0f);

    m.x += bl * (c.x - m.x);
    m.y += bl * (c.y - m.y);
    m.z += bl * (c.z - m.z);
    m.w += bl * (c.w - m.w);

    op[(size_t)f * fs] = m;
    c = n;
  }
}

// ---------------------------------------------------------------------------
extern "C" void kernel_launch(void* const* d_in, const int* in_sizes, int n_in,
                              void* d_out, int out_size, void* d_ws, size_t ws_size,
                              hipStream_t stream) {
  const float* toks  = (const float*)d_in[0];   // [B,F,T,D] f32
  const float* masks = (const float*)d_in[1];   // [B,F,H,W] f32
  float* out = (float*)d_out;                   // [B,F,T,D] f32

  float* partial = (float*)d_ws;                // B*F*COV_SUB = 1024 floats
  float* cov     = partial + B * F * COV_SUB;   // 64 floats

  cov_partial_kernel<<<B * F * COV_SUB, 256, 0, stream>>>(masks, partial);
  cov_final_kernel<<<1, 64, 0, stream>>>(partial, cov);
  tracker_kernel<<<B * T, 256, 0, stream>>>(
      (const float4*)toks, cov, (float4*)out);
}

// Round 4
// 475.063 us; speedup vs baseline: 1.0056x; 1.0056x over previous
//
#include <hip/hip_runtime.h>
#include <math.h>

// Problem constants (match reference)
namespace {
constexpr int B = 2, F = 32, T = 1024, D = 1024;
constexpr int H = 512, W = 512;
constexpr int HWN = H * W;                   // 262144 elements per (b,f) mask
constexpr float BASE_BLEND = 0.1f;           // 1 - DECAY
constexpr float COS_EPS = 1e-6f;
constexpr int COV_SUB = 16;                  // blocks per (b,f) mask slice
}

// ---------------------------------------------------------------------------
// Kernel 1: partial clip+sum of each mask slice. 16 blocks per (b,f) slice so
// the 64MB read uses all CUs. float4 loads, wave shuffle reduce, tiny LDS.
// Writes RAW partial sums; the tracker folds + scales them (no cov_final).
// ---------------------------------------------------------------------------
__global__ __launch_bounds__(256) void cov_partial_kernel(
    const float* __restrict__ masks, float* __restrict__ partial) {
  const int s   = blockIdx.x >> 4;           // (b*F + f) slice
  const int sub = blockIdx.x & (COV_SUB - 1);
  const float4* p = reinterpret_cast<const float4*>(masks) +
                    (size_t)s * (HWN / 4) + (size_t)sub * (HWN / 4 / COV_SUB);
  float sum = 0.f;
#pragma unroll
  for (int i = 0; i < 16; ++i) {             // 16 float4 per thread
    float4 v = p[i * 256 + threadIdx.x];
    sum += fminf(fmaxf(v.x, 0.f), 1.f);
    sum += fminf(fmaxf(v.y, 0.f), 1.f);
    sum += fminf(fmaxf(v.z, 0.f), 1.f);
    sum += fminf(fmaxf(v.w, 0.f), 1.f);
  }
#pragma unroll
  for (int m = 32; m; m >>= 1) sum += __shfl_xor(sum, m, 64);
  __shared__ float sw[4];
  if ((threadIdx.x & 63) == 0) sw[threadIdx.x >> 6] = sum;
  __syncthreads();
  if (threadIdx.x == 0) partial[blockIdx.x] = sw[0] + sw[1] + sw[2] + sw[3];
}

// ---------------------------------------------------------------------------
// Kernel 2: the scan. One BLOCK (256 thr, 4 waves) per (b,t) row; each lane
// holds 1 float4 of the D=1024 memory state. 2048 blocks = 8 blocks/CU.
// Per frame: reduce dot(c,m) and |c|^2 only — |m|^2 is carried by the exact
// recurrence nm' = (1-bl)^2 nm + 2bl(1-bl) dot + bl^2 nc, removing one DOT4
// and one butterfly from the m-dependent chain. One barrier per frame
// (double-buffered LDS slots). Coverage partials folded in the prologue;
// the f=1 barrier fences both smcov and the prologue nm reduction.
// ---------------------------------------------------------------------------
#define DOT4(a, b) ((a).x * (b).x + (a).y * (b).y + (a).z * (b).z + (a).w * (b).w)

__global__ __launch_bounds__(256) void tracker_kernel(
    const float4* __restrict__ toks, const float* __restrict__ partial,
    float4* __restrict__ out) {
  const int tid = threadIdx.x;               // 0..255, float4 index in row
  const int wv  = tid >> 6;
  const int r   = blockIdx.x;                // row index: b*T + t
  const int b   = r >> 10;                   // T = 1024

  const size_t rowbase = ((size_t)(b * F * T) + (size_t)(r & 1023)) * (D / 4);
  const size_t fs      = (size_t)T * (D / 4);  // float4 stride between frames
  const float4* tp = toks + rowbase + tid;
  float4*       op = out  + rowbase + tid;

  __shared__ float red[2][4][2];             // [slot][wave][dot, nc]
  __shared__ float nmred[4];                 // prologue |m0|^2 per wave
  __shared__ float smcov[F];                 // coverage means for this b

  // Prologue A: fold this batch's coverage partials (512 floats from L2).
  if (tid < F) {
    const float* pp = partial + (b * F + tid) * COV_SUB;
    float s = 0.f;
#pragma unroll
    for (int j = 0; j < COV_SUB; ++j) s += pp[j];
    smcov[tid] = s * (1.0f / (float)HWN);
  }

  // f = 0: memory = tokens, copy through.
  float4 m = tp[0];
  op[0] = m;

  // Prologue B: reduce |m0|^2 (butterfly + LDS; fenced by the f=1 barrier).
  {
    float nmp = DOT4(m, m);
#pragma unroll
    for (int msk = 32; msk; msk >>= 1) nmp += __shfl_xor(nmp, msk, 64);
    if ((tid & 63) == 0) nmred[wv] = nmp;
  }

  // prefetch f = 1
  float4 c = tp[fs];
  float nm = 0.f;                            // set at f == 1

  for (int f = 1; f < F; ++f) {
    // prefetch f+1 while we reduce/compute on f
    float4 n;
    if (f + 1 < F) n = tp[(size_t)(f + 1) * fs];

    float dot = DOT4(c, m);
    float nc  = DOT4(c, c);
#pragma unroll
    for (int msk = 32; msk; msk >>= 1) {
      dot += __shfl_xor(dot, msk, 64);
      nc  += __shfl_xor(nc,  msk, 64);
    }
    const int slot = f & 1;
    if ((tid & 63) == 0) {
      red[slot][wv][0] = dot;
      red[slot][wv][1] = nc;
    }
    __syncthreads();
    dot = red[slot][0][0] + red[slot][1][0] + red[slot][2][0] + red[slot][3][0];
    nc  = red[slot][0][1] + red[slot][1][1] + red[slot][2][1] + red[slot][3][1];
    if (f == 1) nm = nmred[0] + nmred[1] + nmred[2] + nmred[3];

    const float sim = dot / (fmaxf(sqrtf(nc), COS_EPS) * fmaxf(sqrtf(nm), COS_EPS));
    float gate = 1.0f / (1.0f + expf(-sim / 0.07f));
    gate *= 0.5f + 0.5f * smcov[f];
    float bl = BASE_BLEND * (0.5f + gate);
    bl = fminf(fmaxf(bl, 0.0f), 1.0f);

    // |m'|^2 recurrence (exact): keeps nm off the reduction next frame.
    const float omb = 1.0f - bl;
    nm = omb * omb * nm + 2.0f * bl * omb * dot + bl * bl * nc;

    m.x += bl * (c.x - m.x);
    m.y += bl * (c.y - m.y);
    m.z += bl * (c.z - m.z);
    m.w += bl * (c.w - m.w);

    op[(size_t)f * fs] = m;
    c = n;
  }
}

// ---------------------------------------------------------------------------
extern "C" void kernel_launch(void* const* d_in, const int* in_sizes, int n_in,
                              void* d_out, int out_size, void* d_ws, size_t ws_size,
                              hipStream_t stream) {
  const float* toks  = (const float*)d_in[0];   // [B,F,T,D] f32
  const float* masks = (const float*)d_in[1];   // [B,F,H,W] f32
  float* out = (float*)d_out;                   // [B,F,T,D] f32

  float* partial = (float*)d_ws;                // B*F*COV_SUB = 1024 floats

  cov_partial_kernel<<<B * F * COV_SUB, 256, 0, stream>>>(masks, partial);
  tracker_kernel<<<B * T, 256, 0, stream>>>(
      (const float4*)toks, partial, (float4*)out);
}